// Round 8
// baseline (180.912 us; speedup 1.0000x reference)
//
#include <hip/hip_runtime.h>

// 4-stream 2-layer LSTM, H=32, T=129, IN=1.
// One block of 256 threads; wave s (=tid>>6) owns stream s end-to-end.
// Lane l owns gate rows l and l+64 (gate order i,f,g,o in blocks of 32).
// R8: replace the 64 v_readlane/step h-broadcast (SGPR-hazard + pressure
// machinery; R3/R6/R7 all ~105us, ~713 instr/step issued vs ~316 essential)
// with LDS broadcast: h written once (lanes<32), read back as 8 wave-uniform
// ds_read_b128 (same-address broadcast, conflict-free). Reads issued early so
// ~120cyc LDS latency hides under independent FMA blocks.

#define HDIM 32
#define SEQT 129
#define NS 4

__device__ __forceinline__ float fsig(float x) {
  return 1.0f / (1.0f + __expf(-x));
}
// lanes<32 receive v[lane+32]; lanes>=32 keep their own value (high-lane
// state is dead in this kernel - only lanes 0..31 are ever read back).
__device__ __forceinline__ float swap_hi(float v) {
  auto r = __builtin_amdgcn_permlane32_swap(__float_as_int(v), __float_as_int(v),
                                            false, false);
  return __int_as_float(r[1]);
}
#define PINF(w) asm volatile("" : "+v"(w))

__global__ __launch_bounds__(256) __attribute__((amdgpu_waves_per_eu(1, 1)))
void lstm4_kernel(const float* __restrict__ x,
                  const float* __restrict__ Wih0, const float* __restrict__ Whh0,
                  const float* __restrict__ bih0, const float* __restrict__ bhh0,
                  const float* __restrict__ Wih1, const float* __restrict__ Whh1,
                  const float* __restrict__ bih1, const float* __restrict__ bhh1,
                  const float* __restrict__ Wt,  const float* __restrict__ bt,
                  const float* __restrict__ Wf1, const float* __restrict__ bf1,
                  const float* __restrict__ Wf2, const float* __restrict__ bf2,
                  float* __restrict__ out) {
  const int tid = threadIdx.x;
  const int s = tid >> 6;   // stream / wave id
  const int l = tid & 63;   // lane

  __shared__ float xs[NS * SEQT + 1];
  __shared__ __align__(16) float hb0[NS][HDIM];   // h0 broadcast buffer
  __shared__ __align__(16) float hb1[NS][HDIM];   // h1 broadcast buffer

  // stage x (S,T,1) -> LDS; zero h buffers (h(-1) = 0)
  for (int i = tid; i < NS * SEQT; i += 256) xs[i] = x[i];
  if (tid == 0) xs[NS * SEQT] = 0.0f;  // prefetch pad
  for (int i = tid; i < NS * HDIM; i += 256) {
    (&hb0[0][0])[i] = 0.0f;
    (&hb1[0][0])[i] = 0.0f;
  }
  __syncthreads();

  const int r1 = s * 128 + l;        // gate row 1 (i or f block)
  const int r2 = s * 128 + l + 64;   // gate row 2 (g or o block)

  // ---- load weight rows into registers (one-time), then PIN them ----
  float wh0a[HDIM], wh0b[HDIM], wi1a[HDIM], wi1b[HDIM], wh1a[HDIM], wh1b[HDIM];
  #pragma unroll
  for (int j = 0; j < 8; ++j) {
    float4 v;
    v = *(const float4*)(Whh0 + r1 * 32 + 4 * j);
    wh0a[4*j] = v.x; wh0a[4*j+1] = v.y; wh0a[4*j+2] = v.z; wh0a[4*j+3] = v.w;
    v = *(const float4*)(Whh0 + r2 * 32 + 4 * j);
    wh0b[4*j] = v.x; wh0b[4*j+1] = v.y; wh0b[4*j+2] = v.z; wh0b[4*j+3] = v.w;
    v = *(const float4*)(Wih1 + r1 * 32 + 4 * j);
    wi1a[4*j] = v.x; wi1a[4*j+1] = v.y; wi1a[4*j+2] = v.z; wi1a[4*j+3] = v.w;
    v = *(const float4*)(Wih1 + r2 * 32 + 4 * j);
    wi1b[4*j] = v.x; wi1b[4*j+1] = v.y; wi1b[4*j+2] = v.z; wi1b[4*j+3] = v.w;
    v = *(const float4*)(Whh1 + r1 * 32 + 4 * j);
    wh1a[4*j] = v.x; wh1a[4*j+1] = v.y; wh1a[4*j+2] = v.z; wh1a[4*j+3] = v.w;
    v = *(const float4*)(Whh1 + r2 * 32 + 4 * j);
    wh1b[4*j] = v.x; wh1b[4*j+1] = v.y; wh1b[4*j+2] = v.z; wh1b[4*j+3] = v.w;
  }
  #pragma unroll
  for (int k = 0; k < HDIM; ++k) {
    PINF(wh0a[k]); PINF(wh0b[k]);
    PINF(wi1a[k]); PINF(wi1b[k]);
    PINF(wh1a[k]); PINF(wh1b[k]);
  }
  const float wx0a = Wih0[r1];
  const float wx0b = Wih0[r2];
  const float b0a  = bih0[r1] + bhh0[r1];
  const float b0b  = bih0[r2] + bhh0[r2];
  const float b1a  = bih1[r1] + bhh1[r1];
  const float b1b  = bih1[r2] + bhh1[r2];

  // gate2 is g (tanh) on lanes<32, o (sigmoid) on lanes>=32.
  // tanh(x) = 2*sigmoid(2x)-1  -> a2 = fma(sigmoid(v2*m2), m2, add2)
  const bool  lo   = (l < 32);
  const float m2   = lo ? 2.0f : 1.0f;
  const float add2 = lo ? -1.0f : 0.0f;

  float c0 = 0.0f, c1 = 0.0f;
  float h1new = 0.0f;

  float hv[HDIM];                       // h0(t-1), register-resident
  #pragma unroll
  for (int k = 0; k < HDIM; ++k) hv[k] = 0.0f;

  float xt = xs[s * SEQT];

  #pragma unroll 1
  for (int t = 0; t < SEQT; ++t) {
    const float xt_next = xs[s * SEQT + t + 1];  // prefetch (pad covers t=128)

    // A: issue h1(t-1) broadcast read early; latency hides under layer-0 FMAs
    float gv[HDIM];
    #pragma unroll
    for (int j = 0; j < 8; ++j) {
      const float4 g4 = *(const float4*)&hb1[s][4 * j];
      gv[4*j] = g4.x; gv[4*j+1] = g4.y; gv[4*j+2] = g4.z; gv[4*j+3] = g4.w;
    }

    // B: layer 0 gates = Whh0 @ h0 + Wih0*x + b
    float p1a = b0a, p1b = 0.f, p1c = 0.f, p1d = 0.f;
    float p2a = b0b, p2b = 0.f, p2c = 0.f, p2d = 0.f;
    p1a = fmaf(wx0a, xt, p1a);
    p2a = fmaf(wx0b, xt, p2a);
    #pragma unroll
    for (int j = 0; j < 8; ++j) {
      p1a = fmaf(wh0a[4*j+0], hv[4*j+0], p1a);
      p1b = fmaf(wh0a[4*j+1], hv[4*j+1], p1b);
      p1c = fmaf(wh0a[4*j+2], hv[4*j+2], p1c);
      p1d = fmaf(wh0a[4*j+3], hv[4*j+3], p1d);
      p2a = fmaf(wh0b[4*j+0], hv[4*j+0], p2a);
      p2b = fmaf(wh0b[4*j+1], hv[4*j+1], p2b);
      p2c = fmaf(wh0b[4*j+2], hv[4*j+2], p2c);
      p2d = fmaf(wh0b[4*j+3], hv[4*j+3], p2d);
    }
    const float v1 = (p1a + p1b) + (p1c + p1d);
    const float v2 = (p2a + p2b) + (p2c + p2d);

    const float a1  = fsig(v1);                 // sigmoid(i) / sigmoid(f)
    const float sv2 = fsig(v2 * m2);
    const float a2  = fmaf(sv2, m2, add2);      // tanh(g) / sigmoid(o)
    const float p   = a1 * a2;                  // i*g on lanes<32
    const float swf = swap_hi(a1);              // lanes<32 get sigmoid(f)
    const float swo = swap_hi(a2);              // lanes<32 get sigmoid(o)
    c0 = fmaf(swf, c0, p);
    const float th0 = fmaf(fsig(2.0f * c0), 2.0f, -1.0f);  // tanh(c0)
    const float h0new = swo * th0;              // valid on lanes<32

    // C: publish h0(t)
    if (lo) hb0[s][l] = h0new;

    // D: read h0(t) broadcast (waits on C via lgkmcnt); latency hides under E
    float hv2[HDIM];
    #pragma unroll
    for (int j = 0; j < 8; ++j) {
      const float4 h4 = *(const float4*)&hb0[s][4 * j];
      hv2[4*j] = h4.x; hv2[4*j+1] = h4.y; hv2[4*j+2] = h4.z; hv2[4*j+3] = h4.w;
    }

    // E: layer 1, Whh1 @ h1(t-1) part (independent of D)
    float q1a = b1a, q1b = 0.f, q1c = 0.f, q1d = 0.f;
    float q2a = b1b, q2b = 0.f, q2c = 0.f, q2d = 0.f;
    #pragma unroll
    for (int j = 0; j < 8; ++j) {
      q1a = fmaf(wh1a[4*j+0], gv[4*j+0], q1a);
      q1b = fmaf(wh1a[4*j+1], gv[4*j+1], q1b);
      q1c = fmaf(wh1a[4*j+2], gv[4*j+2], q1c);
      q1d = fmaf(wh1a[4*j+3], gv[4*j+3], q1d);
      q2a = fmaf(wh1b[4*j+0], gv[4*j+0], q2a);
      q2b = fmaf(wh1b[4*j+1], gv[4*j+1], q2b);
      q2c = fmaf(wh1b[4*j+2], gv[4*j+2], q2c);
      q2d = fmaf(wh1b[4*j+3], gv[4*j+3], q2d);
    }
    // F: layer 1, Wih1 @ h0(t) part
    #pragma unroll
    for (int j = 0; j < 8; ++j) {
      q1a = fmaf(wi1a[4*j+0], hv2[4*j+0], q1a);
      q1b = fmaf(wi1a[4*j+1], hv2[4*j+1], q1b);
      q1c = fmaf(wi1a[4*j+2], hv2[4*j+2], q1c);
      q1d = fmaf(wi1a[4*j+3], hv2[4*j+3], q1d);
      q2a = fmaf(wi1b[4*j+0], hv2[4*j+0], q2a);
      q2b = fmaf(wi1b[4*j+1], hv2[4*j+1], q2b);
      q2c = fmaf(wi1b[4*j+2], hv2[4*j+2], q2c);
      q2d = fmaf(wi1b[4*j+3], hv2[4*j+3], q2d);
    }
    const float w1 = (q1a + q1b) + (q1c + q1d);
    const float w2 = (q2a + q2b) + (q2c + q2d);

    const float A1  = fsig(w1);
    const float sw2 = fsig(w2 * m2);
    const float A2  = fmaf(sw2, m2, add2);
    const float P   = A1 * A2;
    const float SWF = swap_hi(A1);
    const float SWO = swap_hi(A2);
    c1 = fmaf(SWF, c1, P);
    const float th1 = fmaf(fsig(2.0f * c1), 2.0f, -1.0f);
    h1new = SWO * th1;

    // H: publish h1(t) for next step's A-read
    if (lo) hb1[s][l] = h1new;

    // h0(t) stays register-resident for next step's layer 0
    #pragma unroll
    for (int k = 0; k < HDIM; ++k) hv[k] = hv2[k];

    xt = xt_next;
  }

  // ---------- output heads ----------
  __syncthreads();   // hb1 holds final h1 for all 4 streams

  float acc = 0.0f;
  if (s == 0) {
    // targetOut = Wt . concat(h1 streams 0..3) + bt   (128 terms, 2 per lane)
    acc = fmaf(Wt[l], (&hb1[0][0])[l], Wt[l + 64] * (&hb1[0][0])[l + 64]);
  } else {
    const float* Wf = (s == 1) ? Wf1 : Wf2;  // f3 reuses Wf2/bf2 (reference bug kept)
    if (l < HDIM) acc = Wf[l] * hb1[s][l];
  }
  #pragma unroll
  for (int off = 32; off > 0; off >>= 1) acc += __shfl_xor(acc, off);
  if (l == 0) {
    const float bias = (s == 0) ? bt[0] : ((s == 1) ? bf1[0] : bf2[0]);
    out[s] = acc + bias;
  }
}

extern "C" void kernel_launch(void* const* d_in, const int* in_sizes, int n_in,
                              void* d_out, int out_size, void* d_ws, size_t ws_size,
                              hipStream_t stream) {
  const float* x    = (const float*)d_in[0];
  const float* Wih0 = (const float*)d_in[1];
  const float* Whh0 = (const float*)d_in[2];
  const float* bih0 = (const float*)d_in[3];
  const float* bhh0 = (const float*)d_in[4];
  const float* Wih1 = (const float*)d_in[5];
  const float* Whh1 = (const float*)d_in[6];
  const float* bih1 = (const float*)d_in[7];
  const float* bhh1 = (const float*)d_in[8];
  const float* Wt   = (const float*)d_in[9];
  const float* bt   = (const float*)d_in[10];
  const float* Wf1  = (const float*)d_in[11];
  const float* bf1  = (const float*)d_in[12];
  const float* Wf2  = (const float*)d_in[13];
  const float* bf2  = (const float*)d_in[14];
  float* out = (float*)d_out;

  lstm4_kernel<<<1, 256, 0, stream>>>(x, Wih0, Whh0, bih0, bhh0,
                                      Wih1, Whh1, bih1, bhh1,
                                      Wt, bt, Wf1, bf1, Wf2, bf2, out);
}

// Round 9
// 177.461 us; speedup vs baseline: 1.0194x; 1.0194x over previous
//
#include <hip/hip_runtime.h>

// 4-stream 2-layer LSTM, H=32, T=129, IN=1.
// One block of 256 threads; wave s (=tid>>6) owns stream s end-to-end.
// Lane l owns gate rows l and l+64 (gate order i,f,g,o in blocks of 32).
// R9: attack the serial chain (dur invariant at ~810ns/step across 4 variants
// with differing issue counts => latency-floor, likely DVFS ~500-600MHz):
//  - fsig via v_rcp_f32 (kills ~40cyc IEEE fp32 div in 6 sites/step; without
//    -ffast-math 1.0f/x emits div_scale/div_fmas/div_fixup chain)
//  - 8-accumulator FMA trees (4-deep chains instead of 8-deep)
//  - Whh1@h1(t-1) matvec hoisted between L0 matvec and L0 activations
//    (independent work overlapping activation + LDS broadcast latency)

#define HDIM 32
#define SEQT 129
#define NS 4

__device__ __forceinline__ float fsig(float x) {
  return __builtin_amdgcn_rcpf(1.0f + __expf(-x));
}
// lanes<32 receive v[lane+32]; lanes>=32 keep their own value (high-lane
// state is dead in this kernel - only lanes 0..31 are ever read back).
__device__ __forceinline__ float swap_hi(float v) {
  auto r = __builtin_amdgcn_permlane32_swap(__float_as_int(v), __float_as_int(v),
                                            false, false);
  return __int_as_float(r[1]);
}

// dot(w[0..31], h[0..31]) + seed, 8 parallel 4-deep FMA chains
__device__ __forceinline__ float dot32(const float* __restrict__ w,
                                       const float* __restrict__ h, float seed) {
  float a0 = seed, a1 = 0.f, a2 = 0.f, a3 = 0.f;
  float a4 = 0.f, a5 = 0.f, a6 = 0.f, a7 = 0.f;
  #pragma unroll
  for (int j = 0; j < 4; ++j) {
    a0 = fmaf(w[8*j+0], h[8*j+0], a0);
    a1 = fmaf(w[8*j+1], h[8*j+1], a1);
    a2 = fmaf(w[8*j+2], h[8*j+2], a2);
    a3 = fmaf(w[8*j+3], h[8*j+3], a3);
    a4 = fmaf(w[8*j+4], h[8*j+4], a4);
    a5 = fmaf(w[8*j+5], h[8*j+5], a5);
    a6 = fmaf(w[8*j+6], h[8*j+6], a6);
    a7 = fmaf(w[8*j+7], h[8*j+7], a7);
  }
  return ((a0 + a1) + (a2 + a3)) + ((a4 + a5) + (a6 + a7));
}

__global__ __launch_bounds__(256)
void lstm4_kernel(const float* __restrict__ x,
                  const float* __restrict__ Wih0, const float* __restrict__ Whh0,
                  const float* __restrict__ bih0, const float* __restrict__ bhh0,
                  const float* __restrict__ Wih1, const float* __restrict__ Whh1,
                  const float* __restrict__ bih1, const float* __restrict__ bhh1,
                  const float* __restrict__ Wt,  const float* __restrict__ bt,
                  const float* __restrict__ Wf1, const float* __restrict__ bf1,
                  const float* __restrict__ Wf2, const float* __restrict__ bf2,
                  float* __restrict__ out) {
  const int tid = threadIdx.x;
  const int s = tid >> 6;   // stream / wave id
  const int l = tid & 63;   // lane

  __shared__ float xs[NS * SEQT + 1];
  __shared__ __align__(16) float hb0[NS][HDIM];   // h0 broadcast buffer
  __shared__ __align__(16) float hb1[NS][HDIM];   // h1 broadcast buffer

  // stage x (S,T,1) -> LDS; zero h buffers (h(-1) = 0)
  for (int i = tid; i < NS * SEQT; i += 256) xs[i] = x[i];
  if (tid == 0) xs[NS * SEQT] = 0.0f;  // prefetch pad
  for (int i = tid; i < NS * HDIM; i += 256) {
    (&hb0[0][0])[i] = 0.0f;
    (&hb1[0][0])[i] = 0.0f;
  }
  __syncthreads();

  const int r1 = s * 128 + l;        // gate row 1 (i or f block)
  const int r2 = s * 128 + l + 64;   // gate row 2 (g or o block)

  // ---- load weight rows into registers (one-time) ----
  float wh0a[HDIM], wh0b[HDIM], wi1a[HDIM], wi1b[HDIM], wh1a[HDIM], wh1b[HDIM];
  #pragma unroll
  for (int j = 0; j < 8; ++j) {
    float4 v;
    v = *(const float4*)(Whh0 + r1 * 32 + 4 * j);
    wh0a[4*j] = v.x; wh0a[4*j+1] = v.y; wh0a[4*j+2] = v.z; wh0a[4*j+3] = v.w;
    v = *(const float4*)(Whh0 + r2 * 32 + 4 * j);
    wh0b[4*j] = v.x; wh0b[4*j+1] = v.y; wh0b[4*j+2] = v.z; wh0b[4*j+3] = v.w;
    v = *(const float4*)(Wih1 + r1 * 32 + 4 * j);
    wi1a[4*j] = v.x; wi1a[4*j+1] = v.y; wi1a[4*j+2] = v.z; wi1a[4*j+3] = v.w;
    v = *(const float4*)(Wih1 + r2 * 32 + 4 * j);
    wi1b[4*j] = v.x; wi1b[4*j+1] = v.y; wi1b[4*j+2] = v.z; wi1b[4*j+3] = v.w;
    v = *(const float4*)(Whh1 + r1 * 32 + 4 * j);
    wh1a[4*j] = v.x; wh1a[4*j+1] = v.y; wh1a[4*j+2] = v.z; wh1a[4*j+3] = v.w;
    v = *(const float4*)(Whh1 + r2 * 32 + 4 * j);
    wh1b[4*j] = v.x; wh1b[4*j+1] = v.y; wh1b[4*j+2] = v.z; wh1b[4*j+3] = v.w;
  }
  const float wx0a = Wih0[r1];
  const float wx0b = Wih0[r2];
  const float b0a  = bih0[r1] + bhh0[r1];
  const float b0b  = bih0[r2] + bhh0[r2];
  const float b1a  = bih1[r1] + bhh1[r1];
  const float b1b  = bih1[r2] + bhh1[r2];

  // gate2 is g (tanh) on lanes<32, o (sigmoid) on lanes>=32.
  // tanh(x) = 2*sigmoid(2x)-1  -> a2 = fma(sigmoid(v2*m2), m2, add2)
  const bool  lo   = (l < 32);
  const float m2   = lo ? 2.0f : 1.0f;
  const float add2 = lo ? -1.0f : 0.0f;

  float c0 = 0.0f, c1 = 0.0f;
  float h1new = 0.0f;

  float hv[HDIM];                       // h0(t-1), register-resident
  #pragma unroll
  for (int k = 0; k < HDIM; ++k) hv[k] = 0.0f;

  float xt = xs[s * SEQT];

  #pragma unroll 1
  for (int t = 0; t < SEQT; ++t) {
    const float xt_next = xs[s * SEQT + t + 1];  // prefetch (pad covers t=128)

    // A: h1(t-1) broadcast read (latency hides under B)
    float gv[HDIM];
    #pragma unroll
    for (int j = 0; j < 8; ++j) {
      const float4 g4 = *(const float4*)&hb1[s][4 * j];
      gv[4*j] = g4.x; gv[4*j+1] = g4.y; gv[4*j+2] = g4.z; gv[4*j+3] = g4.w;
    }

    // B: layer 0 gates = Whh0 @ h0 + Wih0*x + b
    const float v1 = dot32(wh0a, hv, fmaf(wx0a, xt, b0a));
    const float v2 = dot32(wh0b, hv, fmaf(wx0b, xt, b0b));

    // E(hoisted): layer 1 Whh1 @ h1(t-1) - independent of L0 activations;
    // overlaps the activation chain below.
    const float e1 = dot32(wh1a, gv, b1a);
    const float e2 = dot32(wh1b, gv, b1b);

    // L0 activations
    const float a1  = fsig(v1);                 // sigmoid(i) / sigmoid(f)
    const float sv2 = fsig(v2 * m2);
    const float a2  = fmaf(sv2, m2, add2);      // tanh(g) / sigmoid(o)
    const float p   = a1 * a2;                  // i*g on lanes<32
    const float swf = swap_hi(a1);              // lanes<32 get sigmoid(f)
    const float swo = swap_hi(a2);              // lanes<32 get sigmoid(o)
    c0 = fmaf(swf, c0, p);
    const float th0 = fmaf(fsig(2.0f * c0), 2.0f, -1.0f);  // tanh(c0)
    const float h0new = swo * th0;              // valid on lanes<32

    // C: publish h0(t)
    if (lo) hb0[s][l] = h0new;

    // D: read h0(t) broadcast (waits on C via lgkmcnt)
    float hv2[HDIM];
    #pragma unroll
    for (int j = 0; j < 8; ++j) {
      const float4 h4 = *(const float4*)&hb0[s][4 * j];
      hv2[4*j] = h4.x; hv2[4*j+1] = h4.y; hv2[4*j+2] = h4.z; hv2[4*j+3] = h4.w;
    }

    // F: layer 1 Wih1 @ h0(t), continuing on e1/e2
    const float w1 = dot32(wi1a, hv2, e1);
    const float w2 = dot32(wi1b, hv2, e2);

    const float A1  = fsig(w1);
    const float sw2 = fsig(w2 * m2);
    const float A2  = fmaf(sw2, m2, add2);
    const float P   = A1 * A2;
    const float SWF = swap_hi(A1);
    const float SWO = swap_hi(A2);
    c1 = fmaf(SWF, c1, P);
    const float th1 = fmaf(fsig(2.0f * c1), 2.0f, -1.0f);
    h1new = SWO * th1;

    // H: publish h1(t) for next step's A-read
    if (lo) hb1[s][l] = h1new;

    // h0(t) stays register-resident for next step's layer 0
    #pragma unroll
    for (int k = 0; k < HDIM; ++k) hv[k] = hv2[k];

    xt = xt_next;
  }

  // ---------- output heads ----------
  __syncthreads();   // hb1 holds final h1 for all 4 streams

  float acc = 0.0f;
  if (s == 0) {
    // targetOut = Wt . concat(h1 streams 0..3) + bt   (128 terms, 2 per lane)
    acc = fmaf(Wt[l], (&hb1[0][0])[l], Wt[l + 64] * (&hb1[0][0])[l + 64]);
  } else {
    const float* Wf = (s == 1) ? Wf1 : Wf2;  // f3 reuses Wf2/bf2 (reference bug kept)
    if (l < HDIM) acc = Wf[l] * hb1[s][l];
  }
  #pragma unroll
  for (int off = 32; off > 0; off >>= 1) acc += __shfl_xor(acc, off);
  if (l == 0) {
    const float bias = (s == 0) ? bt[0] : ((s == 1) ? bf1[0] : bf2[0]);
    out[s] = acc + bias;
  }
}

extern "C" void kernel_launch(void* const* d_in, const int* in_sizes, int n_in,
                              void* d_out, int out_size, void* d_ws, size_t ws_size,
                              hipStream_t stream) {
  const float* x    = (const float*)d_in[0];
  const float* Wih0 = (const float*)d_in[1];
  const float* Whh0 = (const float*)d_in[2];
  const float* bih0 = (const float*)d_in[3];
  const float* bhh0 = (const float*)d_in[4];
  const float* Wih1 = (const float*)d_in[5];
  const float* Whh1 = (const float*)d_in[6];
  const float* bih1 = (const float*)d_in[7];
  const float* bhh1 = (const float*)d_in[8];
  const float* Wt   = (const float*)d_in[9];
  const float* bt   = (const float*)d_in[10];
  const float* Wf1  = (const float*)d_in[11];
  const float* bf1  = (const float*)d_in[12];
  const float* Wf2  = (const float*)d_in[13];
  const float* bf2  = (const float*)d_in[14];
  float* out = (float*)d_out;

  lstm4_kernel<<<1, 256, 0, stream>>>(x, Wih0, Whh0, bih0, bhh0,
                                      Wih1, Whh1, bih1, bhh1,
                                      Wt, bt, Wf1, bf1, Wf2, bf2, out);
}

// Round 10
// 154.053 us; speedup vs baseline: 1.1743x; 1.1519x over previous
//
#include <hip/hip_runtime.h>

// 4-stream 2-layer LSTM, H=32, T=129, IN=1.
// One block of 256 threads; wave s (=tid>>6) owns stream s end-to-end.
// Lane l owns gate rows l and l+64 (gate order i,f,g,o in blocks of 32).
// R10: cycles-per-step attack (clock is stuck ~1.0-1.2GHz on a 1-CU kernel;
// R3..R9 показали issue drops w/o time drops => cut BOTH issue and latency):
//  - v_pk_fma_f32 via ext_vector float2 + __builtin_elementwise_fma
//    (halves matvec issue: 192 -> 96 ops/step)
//  - software pipeline: next step's L0 matvec issued BEFORE this step's L1
//    activations (L1 exp/rcp chain off the critical path); no hv copy
//  - LDS broadcast reads placed so independent FMA blocks cover their latency

#define HDIM 32
#define SEQT 129
#define NS 4

typedef float f32x2 __attribute__((ext_vector_type(2)));

__device__ __forceinline__ float fsig(float x) {
  return __builtin_amdgcn_rcpf(1.0f + __expf(-x));
}
// lanes<32 receive v[lane+32]; lanes>=32 keep their own value (high-lane
// state is dead in this kernel - only lanes 0..31 are ever read back).
__device__ __forceinline__ float swap_hi(float v) {
  auto r = __builtin_amdgcn_permlane32_swap(__float_as_int(v), __float_as_int(v),
                                            false, false);
  return __int_as_float(r[1]);
}

// dot(w[0..15]x2, h[0..15]x2) + seed : 16 v_pk_fma_f32 in 4 chains + 3 pk_add
__device__ __forceinline__ float pkdot(const f32x2* __restrict__ w,
                                       const f32x2* __restrict__ h, float seed) {
  f32x2 a0 = {seed, 0.f}, a1 = {0.f, 0.f}, a2 = {0.f, 0.f}, a3 = {0.f, 0.f};
  #pragma unroll
  for (int j = 0; j < 4; ++j) {
    a0 = __builtin_elementwise_fma(w[4*j+0], h[4*j+0], a0);
    a1 = __builtin_elementwise_fma(w[4*j+1], h[4*j+1], a1);
    a2 = __builtin_elementwise_fma(w[4*j+2], h[4*j+2], a2);
    a3 = __builtin_elementwise_fma(w[4*j+3], h[4*j+3], a3);
  }
  const f32x2 r = (a0 + a1) + (a2 + a3);
  return r.x + r.y;
}

__global__ __launch_bounds__(256)
void lstm4_kernel(const float* __restrict__ x,
                  const float* __restrict__ Wih0, const float* __restrict__ Whh0,
                  const float* __restrict__ bih0, const float* __restrict__ bhh0,
                  const float* __restrict__ Wih1, const float* __restrict__ Whh1,
                  const float* __restrict__ bih1, const float* __restrict__ bhh1,
                  const float* __restrict__ Wt,  const float* __restrict__ bt,
                  const float* __restrict__ Wf1, const float* __restrict__ bf1,
                  const float* __restrict__ Wf2, const float* __restrict__ bf2,
                  float* __restrict__ out) {
  const int tid = threadIdx.x;
  const int s = tid >> 6;   // stream / wave id
  const int l = tid & 63;   // lane

  __shared__ float xs[NS * SEQT + 1];
  __shared__ __align__(16) float hb0[NS][HDIM];   // h0 broadcast buffer
  __shared__ __align__(16) float hb1[NS][HDIM];   // h1 broadcast buffer

  // stage x (S,T,1) -> LDS; zero h buffers (h(-1) = 0)
  for (int i = tid; i < NS * SEQT; i += 256) xs[i] = x[i];
  if (tid == 0) xs[NS * SEQT] = 0.0f;  // prefetch pad
  for (int i = tid; i < NS * HDIM; i += 256) {
    (&hb0[0][0])[i] = 0.0f;
    (&hb1[0][0])[i] = 0.0f;
  }
  __syncthreads();

  const int r1 = s * 128 + l;        // gate row 1 (i or f block)
  const int r2 = s * 128 + l + 64;   // gate row 2 (g or o block)

  // ---- load weight rows into registers as f32x2 (one-time) ----
  f32x2 wh0a[16], wh0b[16], wi1a[16], wi1b[16], wh1a[16], wh1b[16];
  #pragma unroll
  for (int j = 0; j < 16; ++j) {
    wh0a[j] = *(const f32x2*)(Whh0 + r1 * 32 + 2 * j);
    wh0b[j] = *(const f32x2*)(Whh0 + r2 * 32 + 2 * j);
    wi1a[j] = *(const f32x2*)(Wih1 + r1 * 32 + 2 * j);
    wi1b[j] = *(const f32x2*)(Wih1 + r2 * 32 + 2 * j);
    wh1a[j] = *(const f32x2*)(Whh1 + r1 * 32 + 2 * j);
    wh1b[j] = *(const f32x2*)(Whh1 + r2 * 32 + 2 * j);
  }
  const float wx0a = Wih0[r1];
  const float wx0b = Wih0[r2];
  const float b0a  = bih0[r1] + bhh0[r1];
  const float b0b  = bih0[r2] + bhh0[r2];
  const float b1a  = bih1[r1] + bhh1[r1];
  const float b1b  = bih1[r2] + bhh1[r2];

  // gate2 is g (tanh) on lanes<32, o (sigmoid) on lanes>=32.
  // tanh(x) = 2*sigmoid(2x)-1  -> a2 = fma(sigmoid(v2*m2), m2, add2)
  const bool  lo   = (l < 32);
  const float m2   = lo ? 2.0f : 1.0f;
  const float add2 = lo ? -1.0f : 0.0f;

  float c0 = 0.0f, c1 = 0.0f;

  // pipeline prologue: L0 pre-activations for t=0 (h0(-1)=0)
  float xt0 = xs[s * SEQT];
  float v1 = fmaf(wx0a, xt0, b0a);
  float v2 = fmaf(wx0b, xt0, b0b);

  #pragma unroll 1
  for (int t = 0; t < SEQT; ++t) {
    // A: h1(t-1) broadcast read; latency covered by L0 activations below
    f32x2 gv[16];
    #pragma unroll
    for (int j = 0; j < 16; ++j) gv[j] = *(const f32x2*)&hb1[s][2 * j];

    const float xtn = xs[s * SEQT + t + 1];  // next x (pad covers t=128)

    // L0 activations for step t (v1,v2 prepared by previous iteration)
    const float a1  = fsig(v1);                 // sigmoid(i) / sigmoid(f)
    const float sv2 = fsig(v2 * m2);
    const float a2  = fmaf(sv2, m2, add2);      // tanh(g) / sigmoid(o)
    const float p   = a1 * a2;                  // i*g on lanes<32
    const float swf = swap_hi(a1);              // lanes<32 get sigmoid(f)
    const float swo = swap_hi(a2);              // lanes<32 get sigmoid(o)
    c0 = fmaf(swf, c0, p);
    const float th0 = fmaf(fsig(2.0f * c0), 2.0f, -1.0f);  // tanh(c0)
    const float h0new = swo * th0;              // valid on lanes<32

    // C: publish h0(t)
    if (lo) hb0[s][l] = h0new;

    // D: read h0(t) broadcast; in-order LDS pipe sees C; latency covered by E
    f32x2 hv[16];
    #pragma unroll
    for (int j = 0; j < 16; ++j) hv[j] = *(const f32x2*)&hb0[s][2 * j];

    // E: layer 1 Whh1 @ h1(t-1) (register gv) - covers D latency
    const float e1 = pkdot(wh1a, gv, b1a);
    const float e2 = pkdot(wh1b, gv, b1b);

    // F: layer 1 Wih1 @ h0(t)
    const float w1 = pkdot(wi1a, hv, e1);
    const float w2 = pkdot(wi1b, hv, e2);

    // B(next): L0 matvec for step t+1 - issued before L1 activations so the
    // L1 exp/rcp chain is off the loop-carried critical path
    v1 = pkdot(wh0a, hv, fmaf(wx0a, xtn, b0a));
    v2 = pkdot(wh0b, hv, fmaf(wx0b, xtn, b0b));

    // L1 activations
    const float A1  = fsig(w1);
    const float sw2 = fsig(w2 * m2);
    const float A2  = fmaf(sw2, m2, add2);
    const float P   = A1 * A2;
    const float SWF = swap_hi(A1);
    const float SWO = swap_hi(A2);
    c1 = fmaf(SWF, c1, P);
    const float th1 = fmaf(fsig(2.0f * c1), 2.0f, -1.0f);
    const float h1new = SWO * th1;

    // H: publish h1(t); next iteration's A-read picks it up
    if (lo) hb1[s][l] = h1new;
  }

  // ---------- output heads ----------
  __syncthreads();   // hb1 holds final h1 for all 4 streams

  float acc = 0.0f;
  if (s == 0) {
    // targetOut = Wt . concat(h1 streams 0..3) + bt   (128 terms, 2 per lane)
    acc = fmaf(Wt[l], (&hb1[0][0])[l], Wt[l + 64] * (&hb1[0][0])[l + 64]);
  } else {
    const float* Wf = (s == 1) ? Wf1 : Wf2;  // f3 reuses Wf2/bf2 (reference bug kept)
    if (l < HDIM) acc = Wf[l] * hb1[s][l];
  }
  #pragma unroll
  for (int off = 32; off > 0; off >>= 1) acc += __shfl_xor(acc, off);
  if (l == 0) {
    const float bias = (s == 0) ? bt[0] : ((s == 1) ? bf1[0] : bf2[0]);
    out[s] = acc + bias;
  }
}

extern "C" void kernel_launch(void* const* d_in, const int* in_sizes, int n_in,
                              void* d_out, int out_size, void* d_ws, size_t ws_size,
                              hipStream_t stream) {
  const float* x    = (const float*)d_in[0];
  const float* Wih0 = (const float*)d_in[1];
  const float* Whh0 = (const float*)d_in[2];
  const float* bih0 = (const float*)d_in[3];
  const float* bhh0 = (const float*)d_in[4];
  const float* Wih1 = (const float*)d_in[5];
  const float* Whh1 = (const float*)d_in[6];
  const float* bih1 = (const float*)d_in[7];
  const float* bhh1 = (const float*)d_in[8];
  const float* Wt   = (const float*)d_in[9];
  const float* bt   = (const float*)d_in[10];
  const float* Wf1  = (const float*)d_in[11];
  const float* bf1  = (const float*)d_in[12];
  const float* Wf2  = (const float*)d_in[13];
  const float* bf2  = (const float*)d_in[14];
  float* out = (float*)d_out;

  lstm4_kernel<<<1, 256, 0, stream>>>(x, Wih0, Whh0, bih0, bhh0,
                                      Wih1, Whh1, bih1, bhh1,
                                      Wt, bt, Wf1, bf1, Wf2, bf2, out);
}